// Round 3
// baseline (1175.792 us; speedup 1.0000x reference)
//
#include <hip/hip_runtime.h>
#include <hip/hip_bf16.h>
#include <math.h>

#define NSRC 8192
#define NTGT 8192
#define DIM 64

// ---------------------------------------------------------------------------
// helpers
// ---------------------------------------------------------------------------
__device__ __forceinline__ float wave_reduce_sum(float x) {
#pragma unroll
  for (int off = 32; off > 0; off >>= 1) x += __shfl_down(x, off, 64);
  return x;
}

__device__ __forceinline__ float bflo(unsigned int u) {  // low bf16 of a u32
  return __uint_as_float(u << 16);
}
__device__ __forceinline__ float bfhi(unsigned int u) {  // high bf16 of a u32
  return __uint_as_float(u & 0xFFFF0000u);
}

// ---------------------------------------------------------------------------
// kernel 1: squared norms of source rows and target rows
// ---------------------------------------------------------------------------
__global__ __launch_bounds__(256) void norms_k(const float* __restrict__ S,
                                               const float* __restrict__ T,
                                               float* __restrict__ s2,
                                               float* __restrict__ t2) {
  int i = blockIdx.x * 256 + threadIdx.x;
  if (i >= NSRC + NTGT) return;
  const float* base = (i < NSRC) ? (S + (size_t)i * DIM)
                                 : (T + (size_t)(i - NSRC) * DIM);
  const float4* p = (const float4*)base;
  float a = 0.f;
#pragma unroll
  for (int k = 0; k < DIM / 4; ++k) {
    float4 v = p[k];
    a += v.x * v.x + v.y * v.y + v.z * v.z + v.w * v.w;
  }
  if (i < NSRC) s2[i] = a;
  else          t2[i - NSRC] = a;
}

// ---------------------------------------------------------------------------
// kernel 2: per-call init. c[]=0 (fallback colsum accumulator), v=1.
// ---------------------------------------------------------------------------
__global__ __launch_bounds__(256) void init_k(float* __restrict__ c,
                                              float* __restrict__ v_out) {
  int i = blockIdx.x * 256 + threadIdx.x;
  if (i < NTGT) {
    c[i] = 0.f;
    v_out[i] = 1.f;
  }
}

// ---------------------------------------------------------------------------
// kernel 3: build K = exp(-cost/eps). Writes bf16 K always; f32 K optional
// (only for the fallback paths).
// ---------------------------------------------------------------------------
#define BM 64
#define BN 128
__global__ __launch_bounds__(256) void kbuild_k(const float* __restrict__ S,
                                                const float* __restrict__ T,
                                                const float* __restrict__ s2,
                                                const float* __restrict__ t2,
                                                float* __restrict__ Kf,
                                                __hip_bfloat16* __restrict__ Kb) {
  __shared__ float sT[BM][68];
  __shared__ float tT[BN][68];
  const int bn = blockIdx.x * BN;
  const int bm = blockIdx.y * BM;
  const int tid = threadIdx.x;

  {
    const float4* sg = (const float4*)(S + (size_t)bm * DIM);
#pragma unroll
    for (int k = 0; k < 4; ++k) {
      int f = tid + 256 * k;
      int row = f >> 4, c4 = f & 15;
      *(float4*)&sT[row][c4 * 4] = sg[f];
    }
    const float4* tg = (const float4*)(T + (size_t)bn * DIM);
#pragma unroll
    for (int k = 0; k < 8; ++k) {
      int f = tid + 256 * k;
      int row = f >> 4, c4 = f & 15;
      *(float4*)&tT[row][c4 * 4] = tg[f];
    }
  }
  __syncthreads();

  const int tx = tid & 15;
  const int ty = tid >> 4;

  float acc[4][8];
#pragma unroll
  for (int a = 0; a < 4; ++a)
#pragma unroll
    for (int b = 0; b < 8; ++b) acc[a][b] = 0.f;

  for (int k = 0; k < DIM; k += 4) {
    float4 sr[4], tr[8];
#pragma unroll
    for (int a = 0; a < 4; ++a) sr[a] = *(float4*)&sT[ty + 16 * a][k];
#pragma unroll
    for (int b = 0; b < 8; ++b) tr[b] = *(float4*)&tT[tx + 16 * b][k];
#pragma unroll
    for (int a = 0; a < 4; ++a)
#pragma unroll
      for (int b = 0; b < 8; ++b) {
        acc[a][b] += sr[a].x * tr[b].x;
        acc[a][b] += sr[a].y * tr[b].y;
        acc[a][b] += sr[a].z * tr[b].z;
        acc[a][b] += sr[a].w * tr[b].w;
      }
  }

#pragma unroll
  for (int a = 0; a < 4; ++a) {
    int gi = bm + ty + 16 * a;
    float s2v = s2[gi];
#pragma unroll
    for (int b = 0; b < 8; ++b) {
      int gj = bn + tx + 16 * b;
      float sq = s2v + t2[gj] - 2.f * acc[a][b];
      float cost = sqrtf(fmaxf(sq, 0.f));
      float kv = __expf(-10.f * cost);  // 1/eps = 10
      size_t off = (size_t)gi * NTGT + gj;
      if (Kf) Kf[off] = kv;
      Kb[off] = __float2bfloat16(kv);
    }
  }
}

// ---------------------------------------------------------------------------
// kernel F: FUSED iteration — one pass over K per Sinkhorn iteration.
// Block owns FI_ROWS rows; 256 threads cooperate per row. Each thread owns a
// fixed 32-column slice: j(s,e) = 8*(tid+256*s)+e, s<4, e<8.
// Per row: dot with v (block reduce -> u_i), then c_reg += K_row * u_i from
// the registers still holding the row chunk. Flush per-block column partials
// (permuted p = (tid+256s)+1024e -> coalesced) to c_part[block][8192].
// Deterministic: no atomics anywhere.
// ---------------------------------------------------------------------------
#define FI_ROWS 16
#define FI_BLOCKS (NSRC / FI_ROWS)  // 512

__global__ __launch_bounds__(256, 4) void fused_iter_k(
    const unsigned short* __restrict__ Kb,
    const float* __restrict__ v,
    float* __restrict__ u_out,
    float* __restrict__ c_part) {
  __shared__ float red[2][4];
  const int tid = threadIdx.x;
  const int wid = tid >> 6, lane = tid & 63;
  const int r0 = blockIdx.x * FI_ROWS;

  float vreg[32], creg[32];
#pragma unroll
  for (int s = 0; s < 4; ++s) {
    const float4* vp = (const float4*)(v + 8 * (tid + 256 * s));
    float4 x = vp[0], y = vp[1];
    vreg[8 * s + 0] = x.x; vreg[8 * s + 1] = x.y;
    vreg[8 * s + 2] = x.z; vreg[8 * s + 3] = x.w;
    vreg[8 * s + 4] = y.x; vreg[8 * s + 5] = y.y;
    vreg[8 * s + 6] = y.z; vreg[8 * s + 7] = y.w;
  }
#pragma unroll
  for (int k = 0; k < 32; ++k) creg[k] = 0.f;

  uint4 qa[4], qb[4];
  {
    const uint4* rp = (const uint4*)(Kb + (size_t)r0 * NTGT);
#pragma unroll
    for (int s = 0; s < 4; ++s) qa[s] = rp[tid + 256 * s];
  }

#define FI_BODY(QCUR, QNXT, R, PAR)                                            \
  {                                                                            \
    const int row = r0 + (R);                                                  \
    /* prefetch next row first so the loads fly under dot+reduce */            \
    if ((R) + 1 < FI_ROWS) {                                                   \
      const uint4* rp = (const uint4*)(Kb + (size_t)(row + 1) * NTGT);         \
      _Pragma("unroll")                                                        \
      for (int s = 0; s < 4; ++s) QNXT[s] = rp[tid + 256 * s];                 \
    }                                                                          \
    float a = 0.f;                                                             \
    _Pragma("unroll")                                                          \
    for (int s = 0; s < 4; ++s) {                                              \
      a += bflo(QCUR[s].x) * vreg[8 * s + 0] + bfhi(QCUR[s].x) * vreg[8 * s + 1]; \
      a += bflo(QCUR[s].y) * vreg[8 * s + 2] + bfhi(QCUR[s].y) * vreg[8 * s + 3]; \
      a += bflo(QCUR[s].z) * vreg[8 * s + 4] + bfhi(QCUR[s].z) * vreg[8 * s + 5]; \
      a += bflo(QCUR[s].w) * vreg[8 * s + 6] + bfhi(QCUR[s].w) * vreg[8 * s + 7]; \
    }                                                                          \
    a = wave_reduce_sum(a);                                                    \
    if (lane == 0) red[PAR][wid] = a;                                          \
    __syncthreads();                                                           \
    float tot = red[PAR][0] + red[PAR][1] + red[PAR][2] + red[PAR][3];         \
    float ui = (1.0f / NSRC) / (tot + 1e-8f);                                  \
    if (tid == 0) u_out[row] = ui;                                             \
    _Pragma("unroll")                                                          \
    for (int s = 0; s < 4; ++s) {                                              \
      creg[8 * s + 0] += bflo(QCUR[s].x) * ui;                                 \
      creg[8 * s + 1] += bfhi(QCUR[s].x) * ui;                                 \
      creg[8 * s + 2] += bflo(QCUR[s].y) * ui;                                 \
      creg[8 * s + 3] += bfhi(QCUR[s].y) * ui;                                 \
      creg[8 * s + 4] += bflo(QCUR[s].z) * ui;                                 \
      creg[8 * s + 5] += bfhi(QCUR[s].z) * ui;                                 \
      creg[8 * s + 6] += bflo(QCUR[s].w) * ui;                                 \
      creg[8 * s + 7] += bfhi(QCUR[s].w) * ui;                                 \
    }                                                                          \
  }

  for (int r = 0; r < FI_ROWS; r += 2) {
    FI_BODY(qa, qb, r, 0)
    FI_BODY(qb, qa, r + 1, 1)
  }
#undef FI_BODY

  // flush: p = (tid+256s) + 1024e, coalesced per (s,e); j(p) = 8*(p&1023)+(p>>10)
  float* dst = c_part + (size_t)blockIdx.x * 8192;
#pragma unroll
  for (int s = 0; s < 4; ++s)
#pragma unroll
    for (int e = 0; e < 8; ++e)
      dst[(tid + 256 * s) + 1024 * e] = creg[8 * s + e];
}

// ---------------------------------------------------------------------------
// kernel F2: stage-1 column reduce: c2[sl][p] = sum over 64 blocks of c_part.
// grid (32, 8); coalesced (fixed p across lanes).
// ---------------------------------------------------------------------------
__global__ __launch_bounds__(256) void csum1_k(const float* __restrict__ c_part,
                                               float* __restrict__ c2) {
  int p = blockIdx.x * 256 + threadIdx.x;
  const float* base = c_part + (size_t)(blockIdx.y * 64) * 8192 + p;
  float a = 0.f;
#pragma unroll 8
  for (int m = 0; m < 64; ++m) a += base[(size_t)m * 8192];
  c2[(size_t)blockIdx.y * 8192 + p] = a;
}

// ---------------------------------------------------------------------------
// kernel F3: stage-2: v[j] = tw / (sum_sl c2[sl][p(j)] + stab).
// ---------------------------------------------------------------------------
__global__ __launch_bounds__(256) void csum2_k(const float* __restrict__ c2,
                                               float* __restrict__ v_out) {
  int j = blockIdx.x * 256 + threadIdx.x;
  int p = (j >> 3) + 1024 * (j & 7);
  float a = 0.f;
#pragma unroll
  for (int sl = 0; sl < 8; ++sl) a += c2[(size_t)sl * 8192 + p];
  v_out[j] = (1.0f / NTGT) / (a + 1e-8f);
}

// ---------------------------------------------------------------------------
// kernel C: coupling from bf16 K: C = u*Kb*v (f32 out), dist partials via
// cost = -0.1*ln(Kb). Guard ln against bf16 underflow (c is 0 there anyway).
// ---------------------------------------------------------------------------
__global__ __launch_bounds__(256) void coupling_bf16_k(
    const unsigned short* __restrict__ Kb,
    const float* __restrict__ u,
    const float* __restrict__ v,
    float* __restrict__ C,
    float* __restrict__ partials) {
  __shared__ float red[4];
  size_t g = (size_t)blockIdx.x * 256 + threadIdx.x;  // 32-elem chunk index
  size_t base = g * 32;
  int i = (int)(base >> 13);
  int j0 = (int)(base & 8191);
  float ui = u[i];
  const uint4* kp = (const uint4*)(Kb + base);
  const float4* vp = (const float4*)(v + j0);
  float part = 0.f;
#pragma unroll
  for (int s = 0; s < 4; ++s) {
    uint4 q = kp[s];
    float4 va = vp[2 * s], vb = vp[2 * s + 1];
    float k0 = bflo(q.x), k1 = bfhi(q.x), k2 = bflo(q.y), k3 = bfhi(q.y);
    float k4 = bflo(q.z), k5 = bfhi(q.z), k6 = bflo(q.w), k7 = bfhi(q.w);
    float c0 = ui * k0 * va.x, c1 = ui * k1 * va.y;
    float c2 = ui * k2 * va.z, c3 = ui * k3 * va.w;
    float c4 = ui * k4 * vb.x, c5 = ui * k5 * vb.y;
    float c6 = ui * k6 * vb.z, c7 = ui * k7 * vb.w;
    part += c0 * __logf(fmaxf(k0, 1e-37f)) + c1 * __logf(fmaxf(k1, 1e-37f)) +
            c2 * __logf(fmaxf(k2, 1e-37f)) + c3 * __logf(fmaxf(k3, 1e-37f)) +
            c4 * __logf(fmaxf(k4, 1e-37f)) + c5 * __logf(fmaxf(k5, 1e-37f)) +
            c6 * __logf(fmaxf(k6, 1e-37f)) + c7 * __logf(fmaxf(k7, 1e-37f));
    float* cw = C + base + 8 * s;
    *(float4*)cw       = make_float4(c0, c1, c2, c3);
    *(float4*)(cw + 4) = make_float4(c4, c5, c6, c7);
  }
  part = wave_reduce_sum(part);
  int wid = threadIdx.x >> 6, lane = threadIdx.x & 63;
  if (lane == 0) red[wid] = part;
  __syncthreads();
  if (threadIdx.x == 0)
    partials[blockIdx.x] = red[0] + red[1] + red[2] + red[3];
}

// ---------------------------------------------------------------------------
// fallback kernels (round-2 path)
// ---------------------------------------------------------------------------
__global__ __launch_bounds__(256) void rowsum_bf16_k(const unsigned short* __restrict__ Kb,
                                                     const float* __restrict__ v,
                                                     float* __restrict__ u_out) {
  int row = (blockIdx.x * 256 + threadIdx.x) >> 6;
  int lane = threadIdx.x & 63;
  const uint4* r4 = (const uint4*)(Kb + (size_t)row * NTGT);
  const float4* v4 = (const float4*)v;
  float a = 0.f;
#pragma unroll 4
  for (int it = lane; it < NTGT / 8; it += 64) {
    uint4 q = r4[it];
    float4 v0 = v4[it * 2];
    float4 v1 = v4[it * 2 + 1];
    a += bflo(q.x) * v0.x + bfhi(q.x) * v0.y;
    a += bflo(q.y) * v0.z + bfhi(q.y) * v0.w;
    a += bflo(q.z) * v1.x + bfhi(q.z) * v1.y;
    a += bflo(q.w) * v1.z + bfhi(q.w) * v1.w;
  }
  a = wave_reduce_sum(a);
  if (lane == 0) u_out[row] = (1.0f / NSRC) / (a + 1e-8f);
}

__global__ __launch_bounds__(256) void rowsum_k(const float* __restrict__ K,
                                                const float* __restrict__ v,
                                                float* __restrict__ u_out) {
  int row = (blockIdx.x * 256 + threadIdx.x) >> 6;
  int lane = threadIdx.x & 63;
  const float4* r4 = (const float4*)(K + (size_t)row * NTGT);
  const float4* v4 = (const float4*)v;
  float a = 0.f;
#pragma unroll 4
  for (int j = lane; j < NTGT / 4; j += 64) {
    float4 k4 = r4[j];
    float4 vv = v4[j];
    a += k4.x * vv.x + k4.y * vv.y + k4.z * vv.z + k4.w * vv.w;
  }
  a = wave_reduce_sum(a);
  if (lane == 0) u_out[row] = (1.0f / NSRC) / (a + 1e-8f);
}

__global__ __launch_bounds__(256) void colsum_bf16_k(const unsigned short* __restrict__ Kb,
                                                     const float* __restrict__ u,
                                                     float* __restrict__ c) {
  int j = blockIdx.x * 2048 + threadIdx.x * 8;
  int i0 = blockIdx.y * 64;
  float a0 = 0.f, a1 = 0.f, a2 = 0.f, a3 = 0.f;
  float a4 = 0.f, a5 = 0.f, a6 = 0.f, a7 = 0.f;
#pragma unroll 8
  for (int i = i0; i < i0 + 64; ++i) {
    float ui = u[i];
    uint4 q = *(const uint4*)(Kb + (size_t)i * NTGT + j);
    a0 += bflo(q.x) * ui; a1 += bfhi(q.x) * ui;
    a2 += bflo(q.y) * ui; a3 += bfhi(q.y) * ui;
    a4 += bflo(q.z) * ui; a5 += bfhi(q.z) * ui;
    a6 += bflo(q.w) * ui; a7 += bfhi(q.w) * ui;
  }
  atomicAdd(&c[j + 0], a0); atomicAdd(&c[j + 1], a1);
  atomicAdd(&c[j + 2], a2); atomicAdd(&c[j + 3], a3);
  atomicAdd(&c[j + 4], a4); atomicAdd(&c[j + 5], a5);
  atomicAdd(&c[j + 6], a6); atomicAdd(&c[j + 7], a7);
}

__global__ __launch_bounds__(256) void colsum_k(const float* __restrict__ K,
                                                const float* __restrict__ u,
                                                float* __restrict__ c) {
  int j = blockIdx.x * 1024 + threadIdx.x * 4;
  int i0 = blockIdx.y * 64;
  float a0 = 0.f, a1 = 0.f, a2 = 0.f, a3 = 0.f;
#pragma unroll 8
  for (int i = i0; i < i0 + 64; ++i) {
    float ui = u[i];
    float4 k4 = *(const float4*)(K + (size_t)i * NTGT + j);
    a0 += k4.x * ui; a1 += k4.y * ui; a2 += k4.z * ui; a3 += k4.w * ui;
  }
  atomicAdd(&c[j + 0], a0);
  atomicAdd(&c[j + 1], a1);
  atomicAdd(&c[j + 2], a2);
  atomicAdd(&c[j + 3], a3);
}

__global__ __launch_bounds__(256) void finishv_k(float* __restrict__ c,
                                                 float* __restrict__ v_out) {
  int j = blockIdx.x * 256 + threadIdx.x;
  v_out[j] = (1.0f / NTGT) / (c[j] + 1e-8f);
  c[j] = 0.f;
}

__global__ __launch_bounds__(256) void coupling_k(float* __restrict__ K,
                                                  const float* __restrict__ u,
                                                  const float* __restrict__ v,
                                                  float* __restrict__ partials) {
  __shared__ float red[4];
  size_t t0 = (size_t)blockIdx.x * 2048 + threadIdx.x;
  float part = 0.f;
#pragma unroll
  for (int s = 0; s < 8; ++s) {
    size_t f4 = t0 + (size_t)s * 256;
    size_t base = f4 * 4;
    int i = (int)(base >> 13);
    int j = (int)(base & 8191);
    float4 k4 = *(float4*)(K + base);
    float ui = u[i];
    float4 vv = *(const float4*)(v + j);
    float c0 = ui * k4.x * vv.x;
    float c1 = ui * k4.y * vv.y;
    float c2 = ui * k4.z * vv.z;
    float c3 = ui * k4.w * vv.w;
    part += c0 * __logf(k4.x) + c1 * __logf(k4.y) +
            c2 * __logf(k4.z) + c3 * __logf(k4.w);
    *(float4*)(K + base) = make_float4(c0, c1, c2, c3);
  }
  part = wave_reduce_sum(part);
  int wid = threadIdx.x >> 6, lane = threadIdx.x & 63;
  if (lane == 0) red[wid] = part;
  __syncthreads();
  if (threadIdx.x == 0)
    partials[blockIdx.x] = red[0] + red[1] + red[2] + red[3];
}

// ---------------------------------------------------------------------------
// kernel 8: dist = -eps * sum(partials) / (ns*nt)
// ---------------------------------------------------------------------------
__global__ __launch_bounds__(256) void finalize_k(const float* __restrict__ partials,
                                                  float* __restrict__ out) {
  __shared__ float red[4];
  float a = 0.f;
  for (int i = threadIdx.x; i < 8192; i += 256) a += partials[i];
  a = wave_reduce_sum(a);
  int wid = threadIdx.x >> 6, lane = threadIdx.x & 63;
  if (lane == 0) red[wid] = a;
  __syncthreads();
  if (threadIdx.x == 0)
    out[0] = (red[0] + red[1] + red[2] + red[3]) *
             (-0.1f / ((float)NSRC * (float)NTGT));
}

// ---------------------------------------------------------------------------
extern "C" void kernel_launch(void* const* d_in, const int* in_sizes, int n_in,
                              void* d_out, int out_size, void* d_ws, size_t ws_size,
                              hipStream_t stream) {
  const float* S = (const float*)d_in[0];
  const float* T = (const float*)d_in[1];
  float* out = (float*)d_out;

  // output layout: [dist(1)][coupling(64M)][u(8192)][v(8192)]
  float* C  = out + 1;
  float* u  = out + 1 + (size_t)NSRC * NTGT;
  float* vv = u + NSRC;

  // ws byte layout:
  //   s2       @ 0        (32 KB)
  //   t2       @ 32K      (32 KB)
  //   c2       @ 64K      (256 KB)
  //   partials @ 320K     (32 KB)
  //   c        @ 352K     (32 KB)   (fallback colsum accumulator)
  //   Kb       @ 512K     (128 MB)
  //   c_part   @ 512K+128M (16 MB)
  char* wsb = (char*)d_ws;
  float* s2       = (float*)(wsb);
  float* t2       = (float*)(wsb + (32 << 10));
  float* c2       = (float*)(wsb + (64 << 10));
  float* partials = (float*)(wsb + (320 << 10));
  float* c        = (float*)(wsb + (352 << 10));
  const size_t KB_OFF = 512 << 10;
  const size_t KB_BYTES = (size_t)NSRC * NTGT * 2;        // 128 MB
  const size_t CP_OFF = KB_OFF + KB_BYTES;
  const size_t CP_BYTES = (size_t)FI_BLOCKS * NTGT * 4;   // 16 MB
  __hip_bfloat16* Kb = (__hip_bfloat16*)(wsb + KB_OFF);
  float* c_part = (float*)(wsb + CP_OFF);

  bool full = ws_size >= CP_OFF + CP_BYTES;   // fused path
  bool mid  = ws_size >= KB_OFF + KB_BYTES;   // round-2 path

  norms_k<<<(NSRC + NTGT + 255) / 256, 256, 0, stream>>>(S, T, s2, t2);
  init_k<<<NTGT / 256, 256, 0, stream>>>(c, vv);

  if (full) {
    kbuild_k<<<dim3(NTGT / BN, NSRC / BM), 256, 0, stream>>>(S, T, s2, t2,
                                                             nullptr, Kb);
    for (int it = 0; it < 10; ++it) {
      fused_iter_k<<<FI_BLOCKS, 256, 0, stream>>>(
          (const unsigned short*)Kb, vv, u, c_part);
      csum1_k<<<dim3(32, 8), 256, 0, stream>>>(c_part, c2);
      csum2_k<<<32, 256, 0, stream>>>(c2, vv);
    }
    coupling_bf16_k<<<8192, 256, 0, stream>>>(
        (const unsigned short*)Kb, u, vv, C, partials);
  } else if (mid) {
    kbuild_k<<<dim3(NTGT / BN, NSRC / BM), 256, 0, stream>>>(S, T, s2, t2,
                                                             C, Kb);
    for (int it = 0; it < 10; ++it) {
      rowsum_bf16_k<<<NSRC * 64 / 256, 256, 0, stream>>>(
          (const unsigned short*)Kb, vv, u);
      colsum_bf16_k<<<dim3(4, 128), 256, 0, stream>>>(
          (const unsigned short*)Kb, u, c);
      finishv_k<<<NTGT / 256, 256, 0, stream>>>(c, vv);
    }
    coupling_k<<<8192, 256, 0, stream>>>(C, u, vv, partials);
  } else {
    kbuild_k<<<dim3(NTGT / BN, NSRC / BM), 256, 0, stream>>>(S, T, s2, t2,
                                                             C, Kb /*unused ok*/);
    for (int it = 0; it < 10; ++it) {
      rowsum_k<<<NSRC * 64 / 256, 256, 0, stream>>>(C, vv, u);
      colsum_k<<<dim3(8, 128), 256, 0, stream>>>(C, u, c);
      finishv_k<<<NTGT / 256, 256, 0, stream>>>(c, vv);
    }
    coupling_k<<<8192, 256, 0, stream>>>(C, u, vv, partials);
  }
  finalize_k<<<1, 256, 0, stream>>>(partials, out);
}